// Round 2
// 158.625 us; speedup vs baseline: 1.0132x; 1.0132x over previous
//
#include <hip/hip_runtime.h>
#include <hip/hip_bf16.h>
#include <stdint.h>

#define HIDDEN 128

typedef __attribute__((ext_vector_type(8))) short short8;
typedef __attribute__((ext_vector_type(4))) unsigned uint4v;
typedef __attribute__((ext_vector_type(4))) float float4v;
typedef __attribute__((ext_vector_type(2))) float float2v;
typedef __attribute__((ext_vector_type(2))) unsigned uint2v;

static __device__ __forceinline__ unsigned short f2bf(float f) {
    union { float f; unsigned u; } v; v.f = f;
    unsigned r = (v.u + 0x7FFFu + ((v.u >> 16) & 1u)) >> 16;
    return (unsigned short)r;
}

// Fast pack f32->bf16 pair: round-half-up (+0x8000) then byte-perm. ±0.5 ULP like RNE.
static __device__ __forceinline__ unsigned pack2bf(float f0, float f1) {
    unsigned u0 = __float_as_uint(f0) + 0x8000u;
    unsigned u1 = __float_as_uint(f1) + 0x8000u;
    return __builtin_amdgcn_perm(u1, u0, 0x07060302u);
}

static __device__ __forceinline__ short8 pack8(float4v lo, float4v hi) {
    uint4v u;
    u[0] = pack2bf(lo[0], lo[1]);
    u[1] = pack2bf(lo[2], lo[3]);
    u[2] = pack2bf(hi[0], hi[1]);
    u[3] = pack2bf(hi[2], hi[3]);
    return *(short8*)&u;
}

// ---------------- prep ----------------
// Wt[j*128+k] = combined W[k][j] (bf16). Permutation within each half:
// physical pp = m*8+tt  <->  logical jj = tt*16+m (b1/W2 permuted to match).
__global__ void prep_wt(const float* __restrict__ W1, const float* __restrict__ b1,
                        const float* __restrict__ W2,
                        unsigned short* __restrict__ Wt,
                        float* __restrict__ b1p, float* __restrict__ W2p) {
    int idx = blockIdx.x * blockDim.x + threadIdx.x;   // 0 .. 32767
    if (idx < 256 * 128) {
        int j = idx >> 7, k = idx & 127;
        float v = (j < 128) ? W1[k * 128 + j] : W1[(128 + k) * 128 + (j - 128)];
        Wt[idx] = f2bf(v);
    }
    if (idx < 128) {
        int m = idx >> 3, tt = idx & 7;
        int jj = tt * 16 + m;
        b1p[idx] = b1[jj];
        W2p[idx] = W2[jj];
    }
}

// ---------------- node GEMM: both halves fused, z read ONCE ----------------
// One block computes BOTH W1 halves for its tiles (previously 2 blocks
// re-read the same z rows). LDS holds all 256 weight cols in 64 KB via
// XOR swizzle (short_idx ^= (col&7)<<3, i.e. byte ^= (col&7)<<4) instead of
// the +8 pad: same <=2-way banking on the 16-row column reads, exact 64 KB.
// Qi[node][h*128+pp] = biased-uint8; dequant v = s*(q-128), s in sA/sB.
__global__ __launch_bounds__(512) void node_gemm(
        const float* __restrict__ z, const unsigned short* __restrict__ Wt,
        const float* __restrict__ b1p,
        unsigned char* __restrict__ Qi, float* __restrict__ sA, float* __restrict__ sB,
        int n_nodes) {
    __shared__ unsigned short Wl[2 * 128 * 128];   // 65536 B

    int tid  = threadIdx.x;
    int lane = tid & 63;
    int wave = tid >> 6;                           // 0..7
    int m    = lane & 15;
    int quad = lane >> 4;

    int nTiles   = (n_nodes + 15) >> 4;
    int tile     = blockIdx.x * 8 + wave;          // one 16-node tile per wave
    bool active  = tile < nTiles;
    int nodebase = tile * 16;
    int row      = nodebase + m;

    // ---- z loads first: independent of LDS, overlap with staging + sync ----
    float4v zr[8];
    {
        bool ok = active && (row < n_nodes);
        const float* zp = z + (size_t)row * HIDDEN + quad * 8;
        #pragma unroll
        for (int s = 0; s < 4; ++s) {
            zr[2 * s]     = ok ? *(const float4v*)(zp + s * 32)     : (float4v)(0.0f);
            zr[2 * s + 1] = ok ? *(const float4v*)(zp + s * 32 + 4) : (float4v)(0.0f);
        }
    }

    // ---- stage BOTH halves' weights into LDS (swizzled) ----
    #pragma unroll
    for (int i = 0; i < 8; ++i) {
        int chunk = tid + i * 512;                 // 0..4095
        int c  = chunk >> 4;                       // global col 0..255 (h folded in)
        int k0 = (chunk & 15) * 8;
        short8 v = *(const short8*)(Wt + chunk * 8);
        int off = c * 128 + k0;
        *(short8*)(Wl + (off ^ ((c & 7) << 3))) = v;
    }
    __syncthreads();
    if (!active) return;

    float4v b1a = *(const float4v*)(b1p + m * 8);
    float4v b1b = *(const float4v*)(b1p + m * 8 + 4);

    short8 a[4];
    #pragma unroll
    for (int s = 0; s < 4; ++s) a[s] = pack8(zr[2 * s], zr[2 * s + 1]);

    #pragma unroll
    for (int h = 0; h < 2; ++h) {
        float4v acc[8];
        #pragma unroll
        for (int t = 0; t < 8; ++t) acc[t] = (float4v)(0.0f);

        int swz = (m & 7) << 3;                    // crow&7 == m&7 (h*128, t*16 are 0 mod 8)
        #pragma unroll
        for (int t = 0; t < 8; ++t) {
            int base = (h * 128 + t * 16 + m) * 128 + quad * 8;
            #pragma unroll
            for (int s = 0; s < 4; ++s) {
                short8 b = *(const short8*)(Wl + ((base + s * 32) ^ swz));
                acc[t] = __builtin_amdgcn_mfma_f32_16x16x32_bf16(a[s], b, acc[t], 0, 0, 0);
            }
        }

        float4v ba = (h == 0) ? b1a : (float4v)(0.0f);
        float4v bb = (h == 0) ? b1b : (float4v)(0.0f);
        float* sArr = (h == 0) ? sA : sB;

        // Epilogue: per node (quad,r): bias-fold, 16-lane row-max, int8 quantize.
        #pragma unroll
        for (int r = 0; r < 4; ++r) {
            int node = nodebase + quad * 4 + r;
            float v[8];
            v[0] = acc[0][r] + ba[0]; v[1] = acc[1][r] + ba[1];
            v[2] = acc[2][r] + ba[2]; v[3] = acc[3][r] + ba[3];
            v[4] = acc[4][r] + bb[0]; v[5] = acc[5][r] + bb[1];
            v[6] = acc[6][r] + bb[2]; v[7] = acc[7][r] + bb[3];

            float amax = fabsf(v[0]);
            #pragma unroll
            for (int t = 1; t < 8; ++t) amax = fmaxf(amax, fabsf(v[t]));
            amax = fmaxf(amax, __shfl_xor(amax, 1));
            amax = fmaxf(amax, __shfl_xor(amax, 2));
            amax = fmaxf(amax, __shfl_xor(amax, 4));
            amax = fmaxf(amax, __shfl_xor(amax, 8));
            amax = fmaxf(amax, 1e-30f);

            float inv = 126.5f * __builtin_amdgcn_rcpf(amax);
            float s   = amax * (1.0f / 126.5f);

            unsigned d0 = 0, d1 = 0;
            #pragma unroll
            for (int t = 0; t < 4; ++t) {
                int q = (int)rintf(fmaf(v[t], inv, 128.0f));
                d0 |= ((unsigned)q & 255u) << (8 * t);
            }
            #pragma unroll
            for (int t = 0; t < 4; ++t) {
                int q = (int)rintf(fmaf(v[4 + t], inv, 128.0f));
                d1 |= ((unsigned)q & 255u) << (8 * t);
            }

            if (node < n_nodes) {
                uint2v pk; pk[0] = d0; pk[1] = d1;
                *(uint2v*)(Qi + (size_t)node * 256 + h * 128 + m * 8) = pk;
                if (m == 0) sArr[node] = s;
            }
        }
    }
}

// ---------------- edge math: packed float2 dequant dot ----------------
static __device__ __forceinline__ float edge_dot8(uint2v u1, uint2v u2,
                                                  float a1, float a2,
                                                  const float2v* w2) {
    float offs = -128.0f * (a1 + a2);
    float2v off2; off2[0] = offs; off2[1] = offs;
    float2v a1v;  a1v[0] = a1;   a1v[1] = a1;
    float2v a2v;  a2v[0] = a2;   a2v[1] = a2;
    float2v acc2; acc2[0] = 0.0f; acc2[1] = 0.0f;
    #pragma unroll
    for (int d = 0; d < 2; ++d) {
        unsigned da = u1[d], db = u2[d];
        #pragma unroll
        for (int p = 0; p < 2; ++p) {
            float2v af, bf;
            af[0] = (float)((da >> (16 * p))     & 255u);
            af[1] = (float)((da >> (16 * p + 8)) & 255u);
            bf[0] = (float)((db >> (16 * p))     & 255u);
            bf[1] = (float)((db >> (16 * p + 8)) & 255u);
            float2v t = a2v * bf + off2;        // v_pk_fma_f32
            float2v s = a1v * af + t;           // v_pk_fma_f32
            s[0] = fmaxf(s[0], 0.0f);
            s[1] = fmaxf(s[1], 0.0f);           // v_pk_max_f32
            acc2 = acc2 + s * w2[2 * d + p];    // v_pk_fma_f32
        }
    }
    return acc2[0] + acc2[1];
}

// ---------------- edge kernel (8 edges/thread, consecutive mapping) --------
// Latency-bound kernel: halve wave count, double per-wave gather MLP (16 Qi
// loads in flight). Group g owns edges ebase..ebase+7 (consecutive) so lane0's
// results store as two float4 -> full-line L2 writes (was: nt 4B scatter with
// 2.9x write amplification).
__global__ __launch_bounds__(256) void edge_kernel(
        const int* __restrict__ eli, const unsigned char* __restrict__ Qi,
        const float* __restrict__ sA, const float* __restrict__ sB,
        const float* __restrict__ W2p, const float* __restrict__ b2,
        float* __restrict__ out, int E) {
    int g      = threadIdx.x >> 4;
    int lane16 = threadIdx.x & 15;
    int j0     = lane16 * 8;

    float2v w2[4];
    #pragma unroll
    for (int k = 0; k < 4; ++k) w2[k] = ((const float2v*)(W2p + j0))[k];
    float bias2 = b2[0];

    int ebase = blockIdx.x * 128 + g * 8;

    int idx_r[8], idx_c[8];
    #pragma unroll
    for (int i = 0; i < 8; ++i) {
        int e = ebase + i;
        bool ok = e < E;
        idx_r[i] = ok ? eli[e]     : 0;
        idx_c[i] = ok ? eli[E + e] : 0;
    }

    uint2v u1[8], u2[8];
    #pragma unroll
    for (int i = 0; i < 8; ++i) {
        u1[i] = *(const uint2v*)(Qi + (size_t)idx_r[i] * 256 + j0);
        u2[i] = *(const uint2v*)(Qi + (size_t)idx_c[i] * 256 + 128 + j0);
    }
    float s1[8], s2[8];
    #pragma unroll
    for (int i = 0; i < 8; ++i) {
        s1[i] = sA[idx_r[i]];
        s2[i] = sB[idx_c[i]];
    }

    float res[8];
    #pragma unroll
    for (int i = 0; i < 8; ++i) {
        float acc = edge_dot8(u1[i], u2[i], s1[i], s2[i], w2);
        acc += __shfl_xor(acc, 1);
        acc += __shfl_xor(acc, 2);
        acc += __shfl_xor(acc, 4);
        acc += __shfl_xor(acc, 8);
        res[i] = acc + bias2;
    }

    if (lane16 == 0) {
        if (ebase + 8 <= E) {
            float4v r0, r1;
            r0[0] = res[0]; r0[1] = res[1]; r0[2] = res[2]; r0[3] = res[3];
            r1[0] = res[4]; r1[1] = res[5]; r1[2] = res[6]; r1[3] = res[7];
            *(float4v*)(out + ebase)     = r0;
            *(float4v*)(out + ebase + 4) = r1;
        } else {
            #pragma unroll
            for (int i = 0; i < 8; ++i)
                if (ebase + i < E) out[ebase + i] = res[i];
        }
    }
}

extern "C" void kernel_launch(void* const* d_in, const int* in_sizes, int n_in,
                              void* d_out, int out_size, void* d_ws, size_t ws_size,
                              hipStream_t stream) {
    const float* z   = (const float*)d_in[0];
    const int*   eli = (const int*)d_in[1];
    const float* W1  = (const float*)d_in[2];
    const float* b1  = (const float*)d_in[3];
    const float* W2  = (const float*)d_in[4];
    const float* b2  = (const float*)d_in[5];
    int n_nodes = in_sizes[0] / HIDDEN;       // 100000
    int E       = in_sizes[1] / 2;            // 1000000
    float* out  = (float*)d_out;

    size_t off = 0;
    unsigned char* Qi  = (unsigned char*)d_ws;                 off += (size_t)n_nodes * 256;
    unsigned short* Wt = (unsigned short*)((char*)d_ws + off); off += 256 * 128 * 2;
    float* b1p = (float*)((char*)d_ws + off);                  off += 128 * 4;
    float* W2p = (float*)((char*)d_ws + off);                  off += 128 * 4;
    float* sA  = (float*)((char*)d_ws + off);                  off += (size_t)n_nodes * 4;
    float* sB  = (float*)((char*)d_ws + off);                  off += (size_t)n_nodes * 4;

    prep_wt<<<128, 256, 0, stream>>>(W1, b1, W2, Wt, b1p, W2p);

    // One block computes both halves for 8 tiles: ceil(6250/8) = 782 blocks.
    int nTiles = (n_nodes + 15) / 16;
    node_gemm<<<(nTiles + 7) / 8, 512, 0, stream>>>(z, Wt, b1p, Qi, sA, sB, n_nodes);

    edge_kernel<<<(E + 127) / 128, 256, 0, stream>>>(eli, Qi, sA, sB, W2p, b2, out, E);
}